// Round 1
// 233.046 us; speedup vs baseline: 1.0392x; 1.0392x over previous
//
#include <hip/hip_runtime.h>
#include <hip/hip_bf16.h>

typedef __bf16 bf16_t;
typedef __bf16 bf16x4 __attribute__((ext_vector_type(4)));
typedef __bf16 bf16x8 __attribute__((ext_vector_type(8)));
typedef float f32x4 __attribute__((ext_vector_type(4)));

#define B_   2
#define L_   4096
#define DIM_ 1024
#define M_   (B_ * L_)          // 8192 total rows

// ---- async global->LDS, 16B per lane (wave-uniform LDS base + lane*16) ----
__device__ __forceinline__ void ld_g2l_16(const bf16_t* g, bf16_t* l) {
  __builtin_amdgcn_global_load_lds(
      (__attribute__((address_space(1))) void*)g,
      (__attribute__((address_space(3))) void*)l, 16, 0, 0);
}

// ---- fused fp32 -> bf16 convert for hs, Wq, Wk (RNE, matches jnp astype) ----
__global__ void cvt_all(const float* __restrict__ hs, const float* __restrict__ wq,
                        const float* __restrict__ wk, bf16_t* __restrict__ hs_b,
                        bf16_t* __restrict__ wq_b, bf16_t* __restrict__ wk_b) {
  const int N_HS = M_ * DIM_ / 4, N_W = DIM_ * DIM_ / 4;
  int i = blockIdx.x * blockDim.x + threadIdx.x;
  const float* s; bf16_t* d; int idx;
  if (i < N_HS)            { s = hs; d = hs_b; idx = i; }
  else if (i < N_HS + N_W) { s = wq; d = wq_b; idx = i - N_HS; }
  else                     { s = wk; d = wk_b; idx = i - N_HS - N_W; }
  float4 v = ((const float4*)s)[idx];
  bf16x4 o = { (bf16_t)v.x, (bf16_t)v.y, (bf16_t)v.z, (bf16_t)v.w };
  ((bf16x4*)d)[idx] = o;
}

// ---- shared 512x128 bt-GEMM core, 8 waves, K=1024 ----
// LDS: 3 buffers x 40 segments x 512 bf16 (A rows 0..511 = segs 0..31,
// B rows 0..127 = segs 32..39). Segments are 16-row x 32-col, XOR-swizzled:
// 16B chunk c of row r lives at slot c ^ ((r>>1)&3); staging lanes fetch the
// permuted global chunk so the fixed lane->lane*16 LDS write lands it
// swizzled; ds_read_b128 then hits each bank exactly 2x (2-way = free).
// Pipeline: depth-2 prefetch, counted vmcnt(5) (loads never drain mid-loop),
// ONE barrier per K-step.
#define SEGS_  40
#define BUFSZ_ (SEGS_ * 512)

__device__ __forceinline__ void stage512(const bf16_t* __restrict__ A,
                                         const bf16_t* __restrict__ B,
                                         int kk, bf16_t* buf,
                                         int wave, int srow, int scol) {
#pragma unroll
  for (int c = 0; c < 4; ++c) {            // A: segs 0..31 (512 rows)
    int seg = c * 8 + wave;
    ld_g2l_16(A + (size_t)(seg * 16 + srow) * DIM_ + kk + scol, buf + seg * 512);
  }
  // B: segs 32..39 (128 rows)
  ld_g2l_16(B + (size_t)(wave * 16 + srow) * DIM_ + kk + scol,
            buf + (32 + wave) * 512);
}

__device__ __forceinline__ void core512(const bf16_t* __restrict__ A,
                                        const bf16_t* __restrict__ B,
                                        bf16_t* sm, bool active,
                                        f32x4 (&acc)[4][8]) {
  const int tid  = threadIdx.x;
  const int wave = tid >> 6, lane = tid & 63;
  const int quad = lane >> 4, l16 = lane & 15;
  const int srow = lane >> 2;                                  // 0..15 in segment
  const int scol = (((lane & 3) ^ ((lane >> 3) & 3)) * 8);     // swizzled chunk
  const int rsw  = ((l16 >> 1) & 3) * 8;                       // read-side swizzle

  bf16_t* r0 = sm;                 // read at t
  bf16_t* r1 = sm + BUFSZ_;        // staged t+1, in flight
  bf16_t* r2 = sm + 2 * BUFSZ_;    // stage target for t+2

  stage512(A, B, 0, r0, wave, srow, scol);     // 5 loads
  stage512(A, B, 32, r1, wave, srow, scol);    // 10 outstanding

  for (int t = 0; t < 32; ++t) {
    // wait tile t's 5 loads (issued 2 iters ago); keep tile t+1's 5 in flight
    if (t < 31) asm volatile("s_waitcnt vmcnt(5)" ::: "memory");
    else        asm volatile("s_waitcnt vmcnt(0)" ::: "memory");
    asm volatile("s_barrier" ::: "memory");    // tile t now valid block-wide

    // prefetch tile t+2 into the buffer everyone finished reading at t-1
    if (t + 2 < 32) stage512(A, B, (t + 2) * 32, r2, wave, srow, scol);

    if (active) {
      bf16x8 af[4], bfr[8];
#pragma unroll
      for (int i = 0; i < 4; ++i)
        af[i] = *(const bf16x8*)(r0 + (wave * 64 + i * 16 + l16) * 32 +
                                 ((quad * 8) ^ rsw));
#pragma unroll
      for (int j = 0; j < 8; ++j)
        bfr[j] = *(const bf16x8*)(r0 + 32 * 512 + (j * 16 + l16) * 32 +
                                  ((quad * 8) ^ rsw));
#pragma unroll
      for (int i = 0; i < 4; ++i)
#pragma unroll
        for (int j = 0; j < 8; ++j)
          acc[i][j] = __builtin_amdgcn_mfma_f32_16x16x32_bf16(af[i], bfr[j],
                                                              acc[i][j], 0, 0, 0);
    }
    // pin this wave's ds_reads complete before its next barrier arrival
    // (next iter stages into r0's buffer) — LDS overwrite race guard
    asm volatile("s_waitcnt lgkmcnt(0)" ::: "memory");
    bf16_t* tmp = r0; r0 = r1; r1 = r2; r2 = tmp;
  }
}

// ---- projection GEMM: C = A @ W^T, 512x128 C-tiles, 256 blocks = 1/CU ----
__global__ __launch_bounds__(512, 2)
void proj_gemm(const bf16_t* __restrict__ A, const bf16_t* __restrict__ Wqb,
               const bf16_t* __restrict__ Wkb, bf16_t* __restrict__ Cq,
               bf16_t* __restrict__ Ck) {
  __shared__ __attribute__((aligned(16))) bf16_t sm[3 * BUFSZ_];
  const bf16_t* Bm = (blockIdx.z == 0) ? Wqb : Wkb;
  bf16_t* Cm = (blockIdx.z == 0) ? Cq : Ck;
  const int m0 = blockIdx.y * 512, n0 = blockIdx.x * 128;

  f32x4 acc[4][8] = {};
  core512(A + (size_t)m0 * DIM_, Bm + (size_t)n0 * DIM_, sm, true, acc);

  const int tid = threadIdx.x, wave = tid >> 6, lane = tid & 63;
  const int quad = lane >> 4, l16 = lane & 15;
#pragma unroll
  for (int i = 0; i < 4; ++i)
#pragma unroll
    for (int j = 0; j < 8; ++j)
#pragma unroll
      for (int r = 0; r < 4; ++r) {
        int m = m0 + wave * 64 + i * 16 + quad * 4 + r;  // C/D: row=quad*4+reg
        int n = n0 + j * 16 + l16;                       //      col=lane&15
        Cm[(size_t)m * DIM_ + n] = (bf16_t)acc[i][j][r];
      }
}

// ---- RoPE in-place, bf16, pairs (j, j+512); blockIdx.y picks q/k ----
__global__ void rope_kernel(bf16_t* __restrict__ q, bf16_t* __restrict__ k) {
  bf16_t* x = blockIdx.y ? k : q;
  int row = blockIdx.x * 2 + (threadIdx.x >> 7);
  int j0  = (threadIdx.x & 127) * 4;
  int pos = row & (L_ - 1);
  bf16_t* p = x + (size_t)row * DIM_;
  bf16x4 v1 = *(const bf16x4*)(p + j0);
  bf16x4 v2 = *(const bf16x4*)(p + j0 + 512);
  bf16x4 o1, o2;
#pragma unroll
  for (int u = 0; u < 4; ++u) {
    int j = j0 + u;
    // inv_freq = 32^(-2j/1024) = 2^(-5j/512)
    float ang = (float)pos * exp2f((float)j * (-5.0f / 512.0f));
    float c = cosf(ang), s = sinf(ang);
    float cb = (float)(bf16_t)c, sb = (float)(bf16_t)s;  // ref rounds cos/sin to bf16
    float x1 = (float)v1[u], x2 = (float)v2[u];
    o1[u] = (bf16_t)(x1 * cb - x2 * sb);
    o2[u] = (bf16_t)(x2 * cb + x1 * sb);
  }
  *(bf16x4*)(p + j0) = o1;
  *(bf16x4*)(p + j0 + 512) = o2;
}

// ---- causal exp-rowsum: o[b,m] = sum_{n<=m} exp(q_m . k_n / 32) ----
// 512x128 tiles, 8 waves. Tasks per batch: mi in 0..7, nt in 0..4mi+3
// (144/batch, 288 total). Static balanced schedule over 256 blocks:
//   bid   0..223 : one full tile  (nt < 4mi), cost 1.0
//   bid 224..239 : diag pair {4mi, 4mi+3}, cost ~1.0+0.25 (wave-row skip)
//   bid 240..255 : diag pair {4mi+1, 4mi+2}, cost ~0.75+0.5
// -> max block load ~1.3 vs 2.0 generations of the old 544/512 layout.
__global__ __launch_bounds__(512, 2)
void attn_rowsum(const bf16_t* __restrict__ Q, const bf16_t* __restrict__ Kc,
                 float* __restrict__ o) {
  __shared__ __attribute__((aligned(16))) bf16_t sm[3 * BUFSZ_];
  const int tid = threadIdx.x, wave = tid >> 6, lane = tid & 63;
  const int quad = lane >> 4, l16 = lane & 15;

  int bid = blockIdx.x;
  int bb, mi, nt0, nt1, ntasks;
  if (bid < 224) {
    bb = bid / 112; int f = bid - bb * 112;
    // fulls before mi: 2*mi*(mi-1); find mi with 2mi(mi-1) <= f < 2mi(mi+1)
    int m = 1;
    while (2 * m * (m + 1) <= f) ++m;
    mi = m; nt0 = f - 2 * m * (m - 1); nt1 = 0; ntasks = 1;
  } else if (bid < 240) {
    int idx = bid - 224; bb = idx >> 3; mi = idx & 7;
    nt0 = 4 * mi; nt1 = 4 * mi + 3; ntasks = 2;
  } else {
    int idx = bid - 240; bb = idx >> 3; mi = idx & 7;
    nt0 = 4 * mi + 1; nt1 = 4 * mi + 2; ntasks = 2;
  }

  const bf16_t* Ab = Q  + (size_t)bb * L_ * DIM_ + (size_t)mi * 512 * DIM_;
  const bf16_t* Kb = Kc + (size_t)bb * L_ * DIM_;

  for (int task = 0; task < ntasks; ++task) {
    int nt = task ? nt1 : nt0;
    if (task) __syncthreads();   // drain all LDS readers before restaging

    // wave-level causal skip: wave rows [mi*512+wave*64, +64) vs cols >= nt*128
    bool active = (mi * 512 + wave * 64 + 63) >= nt * 128;

    f32x4 acc[4][8] = {};
    core512(Ab, Kb + (size_t)nt * 128 * DIM_, sm, active, acc);

    if (active) {
      const bool masked = (nt >= 4 * mi);   // tile touches the diagonal
#pragma unroll
      for (int i = 0; i < 4; ++i) {
#pragma unroll
        for (int r = 0; r < 4; ++r) {
          int grow = mi * 512 + wave * 64 + i * 16 + quad * 4 + r;
          float sum = 0.0f;
#pragma unroll
          for (int j = 0; j < 8; ++j) {
            int gcol = nt * 128 + j * 16 + l16;
            float e = __expf(acc[i][j][r] * 0.03125f);   // /sqrt(1024)
            if (!masked || gcol <= grow) sum += e;
          }
          sum += __shfl_xor(sum, 1);
          sum += __shfl_xor(sum, 2);
          sum += __shfl_xor(sum, 4);
          sum += __shfl_xor(sum, 8);
          if (l16 == 0)
            atomicAdd(&o[bb * L_ + grow], sum);
        }
      }
    }
  }
}

// ---- tiny MLP epilogue ----
__global__ __launch_bounds__(256)
void mlp_out_kernel(const float* __restrict__ o, const float* __restrict__ fc1_w,
                    const float* __restrict__ fc1_b, const float* __restrict__ fc2_w,
                    const float* __restrict__ fc2_b, float* __restrict__ out) {
  const int R = 16;
  int row0 = blockIdx.x * R;
  int tid = threadIdx.x;
  __shared__ float h[R][16];
  {
    int rl = tid >> 4, i = tid & 15;
    float s = o[row0 + rl];
    h[rl][i] = fmaxf(fc1_w[i] * s + fc1_b[i], 0.0f);
  }
  __syncthreads();
  int d = tid * 4;
  float w[4][16];
#pragma unroll
  for (int c = 0; c < 4; ++c)
#pragma unroll
    for (int i = 0; i < 16; ++i) w[c][i] = fc2_w[(d + c) * 16 + i];
  float4 bb = *(const float4*)(fc2_b + d);
  for (int rl = 0; rl < R; ++rl) {
    float4 v = bb;
#pragma unroll
    for (int i = 0; i < 16; ++i) {
      float hv = h[rl][i];
      v.x += w[0][i] * hv; v.y += w[1][i] * hv;
      v.z += w[2][i] * hv; v.w += w[3][i] * hv;
    }
    *(float4*)(out + (size_t)(row0 + rl) * DIM_ + d) = v;
  }
}

extern "C" void kernel_launch(void* const* d_in, const int* in_sizes, int n_in,
                              void* d_out, int out_size, void* d_ws, size_t ws_size,
                              hipStream_t stream) {
  const float* hs    = (const float*)d_in[0];
  const float* Wq    = (const float*)d_in[1];
  const float* Wk    = (const float*)d_in[2];
  const float* fc1_w = (const float*)d_in[3];
  const float* fc1_b = (const float*)d_in[4];
  const float* fc2_w = (const float*)d_in[5];
  const float* fc2_b = (const float*)d_in[6];
  float* out = (float*)d_out;

  char* ws = (char*)d_ws;
  bf16_t* hs_bf = (bf16_t*)ws; ws += (size_t)M_ * DIM_ * 2;
  bf16_t* wq_bf = (bf16_t*)ws; ws += (size_t)DIM_ * DIM_ * 2;
  bf16_t* wk_bf = (bf16_t*)ws; ws += (size_t)DIM_ * DIM_ * 2;
  bf16_t* q_bf  = (bf16_t*)ws; ws += (size_t)M_ * DIM_ * 2;
  bf16_t* k_bf  = (bf16_t*)ws; ws += (size_t)M_ * DIM_ * 2;
  float*  o     = (float*)ws;  // M_ floats

  const int n4 = (M_ * DIM_ + 2 * DIM_ * DIM_) / 4;
  cvt_all<<<n4 / 256, 256, 0, stream>>>(hs, Wq, Wk, hs_bf, wq_bf, wk_bf);

  dim3 gg(DIM_ / 128, M_ / 512, 2);   // 256 blocks, 1/CU
  proj_gemm<<<gg, 512, 0, stream>>>(hs_bf, wq_bf, wk_bf, q_bf, k_bf);

  dim3 gr(M_ / 2, 2);
  rope_kernel<<<gr, 256, 0, stream>>>(q_bf, k_bf);

  hipMemsetAsync(o, 0, M_ * sizeof(float), stream);
  attn_rowsum<<<256, 512, 0, stream>>>(q_bf, k_bf, o);

  mlp_out_kernel<<<M_ / 16, 256, 0, stream>>>(o, fc1_w, fc1_b, fc2_w, fc2_b, out);
}

// Round 2
// 229.491 us; speedup vs baseline: 1.0553x; 1.0155x over previous
//
#include <hip/hip_runtime.h>
#include <hip/hip_bf16.h>

typedef __bf16 bf16_t;
typedef __bf16 bf16x4 __attribute__((ext_vector_type(4)));
typedef __bf16 bf16x8 __attribute__((ext_vector_type(8)));
typedef float f32x4 __attribute__((ext_vector_type(4)));

#define B_   2
#define L_   4096
#define DIM_ 1024
#define M_   (B_ * L_)          // 8192 total rows
#define NTASK2_ 272             // attn tasks/batch: mi 0..15, nt 0..2mi+1

// ---- async global->LDS, 16B per lane (wave-uniform LDS base + lane*16) ----
__device__ __forceinline__ void ld_g2l_16(const bf16_t* g, bf16_t* l) {
  __builtin_amdgcn_global_load_lds(
      (__attribute__((address_space(1))) void*)g,
      (__attribute__((address_space(3))) void*)l, 16, 0, 0);
}

// ---- fused fp32 -> bf16 convert for hs, Wq, Wk (RNE, matches jnp astype) ----
__global__ void cvt_all(const float* __restrict__ hs, const float* __restrict__ wq,
                        const float* __restrict__ wk, bf16_t* __restrict__ hs_b,
                        bf16_t* __restrict__ wq_b, bf16_t* __restrict__ wk_b) {
  const int N_HS = M_ * DIM_ / 4, N_W = DIM_ * DIM_ / 4;
  int i = blockIdx.x * blockDim.x + threadIdx.x;
  const float* s; bf16_t* d; int idx;
  if (i < N_HS)            { s = hs; d = hs_b; idx = i; }
  else if (i < N_HS + N_W) { s = wq; d = wq_b; idx = i - N_HS; }
  else                     { s = wk; d = wk_b; idx = i - N_HS - N_W; }
  float4 v = ((const float4*)s)[idx];
  bf16x4 o = { (bf16_t)v.x, (bf16_t)v.y, (bf16_t)v.z, (bf16_t)v.w };
  ((bf16x4*)d)[idx] = o;
}

// ---- 256x128 bt-GEMM core, 8 waves, fine-interleaved slice pipeline ----
// Tile: BM=256 (A rows), BN=128 (B rows), K in 32-wide slices (32 slices).
// Waves: wm = wave>>1 (4 row-groups of 64), wn = wave&1 (2 col-groups of 64).
// LDS: 3 rotating slice-buffers x 24 segs x 1KB (A segs 0..15, B segs 16..23).
// Segment = 16 rows x 32 k, XOR-swizzled: 16B chunk c of row r at c^((r>>1)&3);
// staging fetches the permuted global chunk so the linear lane*16 LDS write
// lands swizzled; ds_read_b128 is then 2-way-conflict (free, m136).
// Per slice (one phase): {8 ds_read_b128 + 3 global_load_lds -> barrier ->
// lgkmcnt(0) -> setprio(1) 16 MFMA setprio(0) -> vmcnt(3) -> barrier}.
// vmcnt(3) keeps the next slice's 3 loads in flight across the barrier
// (never drains to 0 mid-loop). Safety: buffer written at phase s was last
// read at phase s-1; those reads completed before barrier2(s-1) (each wave
// executed lgkmcnt(0) before arriving), and phase-s stages issue after it.
#define SLICE_SEGS_ 24
#define BUFSZ_ (SLICE_SEGS_ * 512)   // 12288 bf16 = 24 KB per slice buffer

__device__ __forceinline__ void core_256x128_pipe(const bf16_t* __restrict__ A,
                                                  const bf16_t* __restrict__ B,
                                                  bf16_t* sm, bool active,
                                                  f32x4 (&acc)[4][4]) {
  const int tid  = threadIdx.x;
  const int wave = tid >> 6, lane = tid & 63;
  const int wm = wave >> 1, wn = wave & 1;
  const int quad = lane >> 4, l16 = lane & 15;
  const int srow = lane >> 2;                                  // 0..15 in segment
  const int scol = (((lane & 3) ^ ((lane >> 3) & 3)) * 8);     // swizzled chunk
  const int rsw  = ((l16 >> 1) & 3) * 8;                       // read-side swizzle
  const int loff = l16 * 32 + ((quad * 8) ^ rsw);              // frag lane offset

  // this wave's 3 staging sources (segs: A {wave, wave+8}, B {wave})
  const bf16_t* gA0 = A + (size_t)(wave * 16 + srow) * DIM_ + scol;
  const bf16_t* gA1 = A + (size_t)((wave + 8) * 16 + srow) * DIM_ + scol;
  const bf16_t* gB  = B + (size_t)(wave * 16 + srow) * DIM_ + scol;

  bf16_t* p0 = sm;                 // slice s (read)
  bf16_t* p1 = sm + BUFSZ_;        // slice s+1 (in flight)
  bf16_t* p2 = sm + 2 * BUFSZ_;    // slice s+2 (stage target)

  // prologue: stage slices 0,1 (3 loads each per wave)
  ld_g2l_16(gA0,      p0 + wave * 512);
  ld_g2l_16(gA1,      p0 + (wave + 8) * 512);
  ld_g2l_16(gB,       p0 + (16 + wave) * 512);
  ld_g2l_16(gA0 + 32, p1 + wave * 512);
  ld_g2l_16(gA1 + 32, p1 + (wave + 8) * 512);
  ld_g2l_16(gB  + 32, p1 + (16 + wave) * 512);
  gA0 += 64; gA1 += 64; gB += 64;            // next stage = slice 2
  asm volatile("s_waitcnt vmcnt(3)" ::: "memory");   // slice 0 landed
  __builtin_amdgcn_s_barrier();

  for (int s = 0; s < 32; ++s) {
    bf16x8 aF[4], bF[4];
    if (active) {
#pragma unroll
      for (int rf = 0; rf < 4; ++rf)
        aF[rf] = *(const bf16x8*)(p0 + (wm * 4 + rf) * 512 + loff);
#pragma unroll
      for (int cf = 0; cf < 4; ++cf)
        bF[cf] = *(const bf16x8*)(p0 + (16 + wn * 4 + cf) * 512 + loff);
    }
    if (s < 30) {                           // stage slice s+2
      ld_g2l_16(gA0, p2 + wave * 512);
      ld_g2l_16(gA1, p2 + (wave + 8) * 512);
      ld_g2l_16(gB,  p2 + (16 + wave) * 512);
      gA0 += 32; gA1 += 32; gB += 32;
    }
    __builtin_amdgcn_s_barrier();                       // slice s valid
    asm volatile("s_waitcnt lgkmcnt(0)" ::: "memory");  // frags in regs
    __builtin_amdgcn_sched_barrier(0);
    if (active) {
      __builtin_amdgcn_s_setprio(1);
#pragma unroll
      for (int rf = 0; rf < 4; ++rf)
#pragma unroll
        for (int cf = 0; cf < 4; ++cf)
          acc[rf][cf] = __builtin_amdgcn_mfma_f32_16x16x32_bf16(
              aF[rf], bF[cf], acc[rf][cf], 0, 0, 0);
      __builtin_amdgcn_s_setprio(0);
    }
    if (s < 30)       asm volatile("s_waitcnt vmcnt(3)" ::: "memory");
    else if (s == 30) asm volatile("s_waitcnt vmcnt(0)" ::: "memory");
    __builtin_amdgcn_s_barrier();           // readers done; next writer may go
    bf16_t* t0 = p0; p0 = p1; p1 = p2; p2 = t0;
  }
}

// ---- projection GEMM: C = A @ W^T, 256x128 C-tiles, 512 blocks ----
__global__ __launch_bounds__(512, 2)
void proj_gemm(const bf16_t* __restrict__ A, const bf16_t* __restrict__ Wqb,
               const bf16_t* __restrict__ Wkb, bf16_t* __restrict__ Cq,
               bf16_t* __restrict__ Ck) {
  __shared__ __attribute__((aligned(16))) bf16_t sm[3 * BUFSZ_];
  const bf16_t* Bm = (blockIdx.z == 0) ? Wqb : Wkb;
  bf16_t* Cm = (blockIdx.z == 0) ? Cq : Ck;
  const int m0 = blockIdx.y * 256, n0 = blockIdx.x * 128;

  f32x4 acc[4][4] = {};
  core_256x128_pipe(A + (size_t)m0 * DIM_, Bm + (size_t)n0 * DIM_, sm, true, acc);

  const int tid = threadIdx.x, wave = tid >> 6, lane = tid & 63;
  const int wm = wave >> 1, wn = wave & 1;
  const int quad = lane >> 4, l16 = lane & 15;
#pragma unroll
  for (int rf = 0; rf < 4; ++rf)
#pragma unroll
    for (int cf = 0; cf < 4; ++cf)
#pragma unroll
      for (int r = 0; r < 4; ++r) {
        int m = m0 + wm * 64 + rf * 16 + quad * 4 + r;  // C/D: row=quad*4+reg
        int n = n0 + wn * 64 + cf * 16 + l16;           //      col=lane&15
        Cm[(size_t)m * DIM_ + n] = (bf16_t)acc[rf][cf][r];
      }
}

// ---- RoPE in-place, bf16, pairs (j, j+512); blockIdx.y picks q/k ----
__global__ void rope_kernel(bf16_t* __restrict__ q, bf16_t* __restrict__ k) {
  bf16_t* x = blockIdx.y ? k : q;
  int row = blockIdx.x * 2 + (threadIdx.x >> 7);
  int j0  = (threadIdx.x & 127) * 4;
  int pos = row & (L_ - 1);
  bf16_t* p = x + (size_t)row * DIM_;
  bf16x4 v1 = *(const bf16x4*)(p + j0);
  bf16x4 v2 = *(const bf16x4*)(p + j0 + 512);
  bf16x4 o1, o2;
#pragma unroll
  for (int u = 0; u < 4; ++u) {
    int j = j0 + u;
    // inv_freq = 32^(-2j/1024) = 2^(-5j/512)
    float ang = (float)pos * exp2f((float)j * (-5.0f / 512.0f));
    float c = cosf(ang), s = sinf(ang);
    float cb = (float)(bf16_t)c, sb = (float)(bf16_t)s;  // ref rounds cos/sin to bf16
    float x1 = (float)v1[u], x2 = (float)v2[u];
    o1[u] = (bf16_t)(x1 * cb - x2 * sb);
    o2[u] = (bf16_t)(x2 * cb + x1 * sb);
  }
  *(bf16x4*)(p + j0) = o1;
  *(bf16x4*)(p + j0 + 512) = o2;
}

// ---- causal exp-rowsum: o[b,m] = sum_{n<=m} exp(q_m . k_n / 32) ----
// 256x128 tiles; per batch: mi in 0..15, nt in 0..2mi+1 -> 272 tasks
__global__ __launch_bounds__(512, 2)
void attn_rowsum(const bf16_t* __restrict__ Q, const bf16_t* __restrict__ Kc,
                 float* __restrict__ o) {
  __shared__ __attribute__((aligned(16))) bf16_t sm[3 * BUFSZ_];
  int t = blockIdx.x;
  int b = t / NTASK2_;
  t -= b * NTASK2_;
  int mi = (int)((sqrtf(4.0f * (float)t + 1.0f) - 1.0f) * 0.5f);
  while ((mi + 1) * (mi + 2) <= t) ++mi;     // (mi+1)^2+(mi+1) <= t
  while (mi * (mi + 1) > t) --mi;            // mi^2+mi > t
  int nt = t - mi * (mi + 1);

  const int tid = threadIdx.x, wave = tid >> 6, lane = tid & 63;
  const int wm = wave >> 1, wn = wave & 1;
  const int quad = lane >> 4, l16 = lane & 15;

  const bf16_t* A  = Q  + (size_t)b * L_ * DIM_ + (size_t)mi * 256 * DIM_;
  const bf16_t* Bp = Kc + (size_t)b * L_ * DIM_ + (size_t)nt * 128 * DIM_;

  // wave-level causal skip: wave rows [mi*256+wm*64, +64) vs cols >= nt*128
  bool active = (mi * 256 + wm * 64 + 63) >= nt * 128;

  f32x4 acc[4][4] = {};
  core_256x128_pipe(A, Bp, sm, active, acc);

  if (active) {
    const bool masked = (nt >= 2 * mi);   // tile touches the diagonal
#pragma unroll
    for (int rf = 0; rf < 4; ++rf) {
#pragma unroll
      for (int r = 0; r < 4; ++r) {
        int grow = mi * 256 + wm * 64 + rf * 16 + quad * 4 + r;  // row in batch
        float sum = 0.0f;
#pragma unroll
        for (int cf = 0; cf < 4; ++cf) {
          int gcol = nt * 128 + wn * 64 + cf * 16 + l16;
          float e = __expf(acc[rf][cf][r] * 0.03125f);   // /sqrt(1024)
          if (!masked || gcol <= grow) sum += e;
        }
        sum += __shfl_xor(sum, 1);
        sum += __shfl_xor(sum, 2);
        sum += __shfl_xor(sum, 4);
        sum += __shfl_xor(sum, 8);
        if (l16 == 0)
          atomicAdd(&o[b * L_ + grow], sum);
      }
    }
  }
}

// ---- tiny MLP epilogue ----
__global__ __launch_bounds__(256)
void mlp_out_kernel(const float* __restrict__ o, const float* __restrict__ fc1_w,
                    const float* __restrict__ fc1_b, const float* __restrict__ fc2_w,
                    const float* __restrict__ fc2_b, float* __restrict__ out) {
  const int R = 16;
  int row0 = blockIdx.x * R;
  int tid = threadIdx.x;
  __shared__ float h[R][16];
  {
    int rl = tid >> 4, i = tid & 15;
    float s = o[row0 + rl];
    h[rl][i] = fmaxf(fc1_w[i] * s + fc1_b[i], 0.0f);
  }
  __syncthreads();
  int d = tid * 4;
  float w[4][16];
#pragma unroll
  for (int c = 0; c < 4; ++c)
#pragma unroll
    for (int i = 0; i < 16; ++i) w[c][i] = fc2_w[(d + c) * 16 + i];
  float4 bb = *(const float4*)(fc2_b + d);
  for (int rl = 0; rl < R; ++rl) {
    float4 v = bb;
#pragma unroll
    for (int i = 0; i < 16; ++i) {
      float hv = h[rl][i];
      v.x += w[0][i] * hv; v.y += w[1][i] * hv;
      v.z += w[2][i] * hv; v.w += w[3][i] * hv;
    }
    *(float4*)(out + (size_t)(row0 + rl) * DIM_ + d) = v;
  }
}

extern "C" void kernel_launch(void* const* d_in, const int* in_sizes, int n_in,
                              void* d_out, int out_size, void* d_ws, size_t ws_size,
                              hipStream_t stream) {
  const float* hs    = (const float*)d_in[0];
  const float* Wq    = (const float*)d_in[1];
  const float* Wk    = (const float*)d_in[2];
  const float* fc1_w = (const float*)d_in[3];
  const float* fc1_b = (const float*)d_in[4];
  const float* fc2_w = (const float*)d_in[5];
  const float* fc2_b = (const float*)d_in[6];
  float* out = (float*)d_out;

  char* ws = (char*)d_ws;
  bf16_t* hs_bf = (bf16_t*)ws; ws += (size_t)M_ * DIM_ * 2;
  bf16_t* wq_bf = (bf16_t*)ws; ws += (size_t)DIM_ * DIM_ * 2;
  bf16_t* wk_bf = (bf16_t*)ws; ws += (size_t)DIM_ * DIM_ * 2;
  bf16_t* q_bf  = (bf16_t*)ws; ws += (size_t)M_ * DIM_ * 2;
  bf16_t* k_bf  = (bf16_t*)ws; ws += (size_t)M_ * DIM_ * 2;
  float*  o     = (float*)ws;  // M_ floats

  const int n4 = (M_ * DIM_ + 2 * DIM_ * DIM_) / 4;
  cvt_all<<<n4 / 256, 256, 0, stream>>>(hs, Wq, Wk, hs_bf, wq_bf, wk_bf);

  dim3 gg(DIM_ / 128, M_ / 256, 2);   // 512 blocks, 2 clean generations
  proj_gemm<<<gg, 512, 0, stream>>>(hs_bf, wq_bf, wk_bf, q_bf, k_bf);

  dim3 gr(M_ / 2, 2);
  rope_kernel<<<gr, 256, 0, stream>>>(q_bf, k_bf);

  hipMemsetAsync(o, 0, M_ * sizeof(float), stream);
  attn_rowsum<<<B_ * NTASK2_, 512, 0, stream>>>(q_bf, k_bf, o);

  mlp_out_kernel<<<M_ / 16, 256, 0, stream>>>(o, fc1_w, fc1_b, fc2_w, fc2_b, out);
}